// Round 5
// baseline (194.844 us; speedup 1.0000x reference)
//
#include <hip/hip_runtime.h>
#include <hip/hip_cooperative_groups.h>
#include <float.h>
#include <math.h>

namespace cg = cooperative_groups;

// Problem constants (from reference)
constexpr int B  = 16;
constexpr int VS = 10475;
constexpr int VO = 8192;
constexpr int K  = 64;
constexpr int PS = 1024;
constexpr int PO = 2048;

// Fused-kernel geometry (VALU-bound optimum from R4):
//   BLK=128, Q=8 -> each LDS broadcast feeds 32 VALU inst (LDS 5.1us < VALU 6.8us per CU)
//   JC=16 -> 1024 blocks = 4/CU co-resident (needs ~64 VGPR, 2.5KB LDS; capacity ~12/CU)
constexpr int JC     = 16;
constexpr int JCHUNK = PO / JC;       // 128
constexpr int BLK    = 128;
constexpr int Q      = PS / BLK;      // 8
constexpr int GRID   = K * JC;        // 1024
constexpr int RB     = 256;           // reduction blocks in phase B

// ---------------- single cooperative kernel ----------------

__global__ __launch_bounds__(BLK)
void cl_fused(const float* __restrict__ smplx_v,
              const float* __restrict__ object_v,
              const int*   __restrict__ spi,
              const int*   __restrict__ opi,
              const int*   __restrict__ bidx,
              float*       __restrict__ partial,   // [JC][K][PS]
              float*       __restrict__ part2,     // [RB]
              float*       __restrict__ out)
{
    cg::grid_group grid = cg::this_grid();

    __shared__ float4 so[JCHUNK];    // (ox,oy,oz, 0.5*|o|^2) -> 2 KiB
    __shared__ float  red[BLK];

    const int blk = blockIdx.x;
    const int tid = threadIdx.x;
    const int k   = blk / JC;
    const int jc  = blk % JC;

    // ---- phase A: gather + partial min over this jc chunk ----
    {
        const int b = bidx[k];
        const float* __restrict__ ov = object_v + (size_t)b * VO * 3;

        const int oj = opi[k * PO + jc * JCHUNK + tid];
        const float ox = ov[oj * 3 + 0];
        const float oy = ov[oj * 3 + 1];
        const float oz = ov[oj * 3 + 2];
        so[tid] = make_float4(ox, oy, oz, 0.5f * (ox * ox + oy * oy + oz * oz));

        float sx[Q], sy[Q], sz[Q], s2[Q], mint[Q];
        const float* __restrict__ svb = smplx_v + (size_t)b * VS * 3;
        #pragma unroll
        for (int q = 0; q < Q; ++q) {
            const int i  = tid + q * BLK;
            const int si = spi[k * PS + i];
            const float* __restrict__ sv = svb + (size_t)si * 3;
            sx[q] = sv[0]; sy[q] = sv[1]; sz[q] = sv[2];
            s2[q] = sx[q] * sx[q] + sy[q] * sy[q] + sz[q] * sz[q];
            mint[q] = FLT_MAX;
        }
        __syncthreads();

        #pragma unroll 4
        for (int j = 0; j < JCHUNK; j += 2) {
            const float4 o0 = so[j];
            const float4 o1 = so[j + 1];
            #pragma unroll
            for (int q = 0; q < Q; ++q) {
                const float t0 = fmaf(o0.z, -sz[q], fmaf(o0.y, -sy[q], fmaf(o0.x, -sx[q], o0.w)));
                const float t1 = fmaf(o1.z, -sz[q], fmaf(o1.y, -sy[q], fmaf(o1.x, -sx[q], o1.w)));
                mint[q] = fminf(mint[q], fminf(t0, t1));
            }
        }

        float* __restrict__ dst = partial + ((size_t)jc * K + k) * PS;
        #pragma unroll
        for (int q = 0; q < Q; ++q)
            dst[tid + q * BLK] = fmaxf(fmaf(2.0f, mint[q], s2[q]), 0.0f);
    }

    grid.sync();

    // ---- phase B: min over jc, sqrt, per-block sum (blocks 0..RB-1) ----
    if (blk < RB) {
        const int kk    = blk >> 2;            // 4 blocks per k
        const int ibase = (blk & 3) * 256;
        float sum = 0.0f;
        #pragma unroll
        for (int r = 0; r < 2; ++r) {
            const int i = ibase + r * BLK + tid;
            const float* __restrict__ p = partial + (size_t)kk * PS + i;
            float m = p[0];
            #pragma unroll
            for (int jj = 1; jj < JC; ++jj)
                m = fminf(m, p[(size_t)jj * (K * PS)]);
            sum += sqrtf(m);
        }
        red[tid] = sum;
        __syncthreads();
        for (int s = BLK / 2; s > 0; s >>= 1) {
            if (tid < s) red[tid] += red[tid + s];
            __syncthreads();
        }
        if (tid == 0) part2[blk] = red[0];
    }

    grid.sync();

    // ---- phase C: final sum (block 0) ----
    if (blk == 0) {
        float v = part2[tid] + part2[tid + BLK];
        red[tid] = v;
        __syncthreads();
        for (int s = BLK / 2; s > 0; s >>= 1) {
            if (tid < s) red[tid] += red[tid + s];
            __syncthreads();
        }
        if (tid == 0) out[0] = red[0] * (1.0f / (float)(K * PS));
    }
}

// ---------------- fallback: R4's passing 4-kernel path ----------------

constexpr int P2_BLOCK  = 256;
constexpr int P2_GRID   = (K * PS) / P2_BLOCK;  // 256
constexpr int PREP_GRID = (K * PS) / 256;       // 256

__global__ __launch_bounds__(256)
void cl_gather_q(const float* __restrict__ smplx_v,
                 const int*   __restrict__ smpl_part_idx,
                 const int*   __restrict__ batch_idx,
                 float4*      __restrict__ qg)
{
    const int gid = blockIdx.x * 256 + threadIdx.x;
    const int k   = gid / PS;
    const int b   = batch_idx[k];
    const int si  = smpl_part_idx[gid];
    const float* __restrict__ sv = smplx_v + ((size_t)b * VS + si) * 3;
    const float sx = sv[0], sy = sv[1], sz = sv[2];
    qg[gid] = make_float4(sx, sy, sz, sx * sx + sy * sy + sz * sz);
}

__global__ __launch_bounds__(BLK)
void cl_pass1(const float* __restrict__ object_v,
              const int*   __restrict__ obj_part_idx,
              const int*   __restrict__ batch_idx,
              const float4* __restrict__ qg,
              float*       __restrict__ partial)
{
    __shared__ float4 so[JCHUNK];
    const int blk = blockIdx.x;
    const int k   = blk / JC;
    const int jc  = blk % JC;
    const int tid = threadIdx.x;

    const int b = batch_idx[k];
    const float* __restrict__ ov = object_v + (size_t)b * VO * 3;
    {
        const int oj = obj_part_idx[k * PO + jc * JCHUNK + tid];
        const float ox = ov[oj * 3 + 0];
        const float oy = ov[oj * 3 + 1];
        const float oz = ov[oj * 3 + 2];
        so[tid] = make_float4(ox, oy, oz, 0.5f * (ox * ox + oy * oy + oz * oz));
    }
    float sx[Q], sy[Q], sz[Q], s2[Q], mint[Q];
    const float4* __restrict__ q4 = qg + (size_t)k * PS;
    #pragma unroll
    for (int q = 0; q < Q; ++q) {
        const float4 s = q4[tid + q * BLK];
        sx[q] = s.x; sy[q] = s.y; sz[q] = s.z; s2[q] = s.w;
        mint[q] = FLT_MAX;
    }
    __syncthreads();
    #pragma unroll 4
    for (int j = 0; j < JCHUNK; j += 2) {
        const float4 o0 = so[j];
        const float4 o1 = so[j + 1];
        #pragma unroll
        for (int q = 0; q < Q; ++q) {
            const float t0 = fmaf(o0.z, -sz[q], fmaf(o0.y, -sy[q], fmaf(o0.x, -sx[q], o0.w)));
            const float t1 = fmaf(o1.z, -sz[q], fmaf(o1.y, -sy[q], fmaf(o1.x, -sx[q], o1.w)));
            mint[q] = fminf(mint[q], fminf(t0, t1));
        }
    }
    float* __restrict__ dst = partial + ((size_t)jc * K + k) * PS;
    #pragma unroll
    for (int q = 0; q < Q; ++q)
        dst[tid + q * BLK] = fmaxf(fmaf(2.0f, mint[q], s2[q]), 0.0f);
}

__global__ __launch_bounds__(P2_BLOCK)
void cl_pass2(const float* __restrict__ partial,
              float*       __restrict__ part2)
{
    __shared__ float red[P2_BLOCK];
    const int blk = blockIdx.x;
    const int tid = threadIdx.x;
    const int k   = blk >> 2;
    const int i   = (blk & 3) * P2_BLOCK + tid;

    const float* __restrict__ p = partial + (size_t)k * PS + i;
    float m = p[0];
    #pragma unroll
    for (int jc = 1; jc < JC; ++jc)
        m = fminf(m, p[(size_t)jc * (K * PS)]);
    const float v = sqrtf(m);

    red[tid] = v;
    __syncthreads();
    for (int s = P2_BLOCK / 2; s > 0; s >>= 1) {
        if (tid < s) red[tid] += red[tid + s];
        __syncthreads();
    }
    if (tid == 0) part2[blk] = red[0];
}

__global__ __launch_bounds__(P2_GRID)
void cl_pass3(const float* __restrict__ part2, float* __restrict__ out)
{
    __shared__ float red[P2_GRID];
    const int tid = threadIdx.x;
    red[tid] = part2[tid];
    __syncthreads();
    for (int s = P2_GRID / 2; s > 0; s >>= 1) {
        if (tid < s) red[tid] += red[tid + s];
        __syncthreads();
    }
    if (tid == 0) out[0] = red[0] * (1.0f / (float)(K * PS));
}

// ---------------- launcher ----------------

extern "C" void kernel_launch(void* const* d_in, const int* in_sizes, int n_in,
                              void* d_out, int out_size, void* d_ws, size_t ws_size,
                              hipStream_t stream)
{
    const float* smplx_v       = (const float*)d_in[0];
    const float* object_v      = (const float*)d_in[1];
    const int*   smpl_part_idx = (const int*)d_in[2];
    const int*   obj_part_idx  = (const int*)d_in[3];
    const int*   batch_idx     = (const int*)d_in[4];
    float*       out           = (float*)d_out;

    // ws layout (fused): partial [JC*K*PS floats] | part2 [RB floats]
    // ws layout (fallback adds): qg [K*PS float4] after those.
    const size_t partial_elems = (size_t)JC * K * PS;            // 1M floats
    const size_t qg_elems      = (size_t)K * PS;
    const size_t need_fused    = (partial_elems + RB) * sizeof(float);
    const size_t need_fb       = need_fused + qg_elems * sizeof(float4);

    if (ws_size >= need_fused) {
        float* partial = (float*)d_ws;
        float* part2   = partial + partial_elems;

        void* args[] = {
            (void*)&smplx_v, (void*)&object_v,
            (void*)&smpl_part_idx, (void*)&obj_part_idx, (void*)&batch_idx,
            (void*)&partial, (void*)&part2, (void*)&out
        };
        hipError_t err = hipLaunchCooperativeKernel(
            (const void*)cl_fused, dim3(GRID), dim3(BLK), args, 0, stream);

        if (err == hipSuccess) return;

        // cooperative launch unavailable -> fall through to 4-kernel path
        if (ws_size >= need_fb) {
            float4* qg = (float4*)(part2 + RB);
            cl_gather_q<<<PREP_GRID, 256, 0, stream>>>(
                smplx_v, smpl_part_idx, batch_idx, qg);
            cl_pass1<<<GRID, BLK, 0, stream>>>(
                object_v, obj_part_idx, batch_idx, qg, partial);
            cl_pass2<<<P2_GRID, P2_BLOCK, 0, stream>>>(partial, part2);
            cl_pass3<<<1, P2_GRID, 0, stream>>>(part2, out);
            return;
        }
    }

    // minimal-ws fallback: 4-kernel path with qg at base (needs ~5MB)
    {
        float4* qg      = (float4*)d_ws;
        float*  partial = (float*)(qg + qg_elems);
        float*  part2   = partial + partial_elems;
        cl_gather_q<<<PREP_GRID, 256, 0, stream>>>(
            smplx_v, smpl_part_idx, batch_idx, qg);
        cl_pass1<<<GRID, BLK, 0, stream>>>(
            object_v, obj_part_idx, batch_idx, qg, partial);
        cl_pass2<<<P2_GRID, P2_BLOCK, 0, stream>>>(partial, part2);
        cl_pass3<<<1, P2_GRID, 0, stream>>>(part2, out);
    }
}

// Round 6
// 21.323 us; speedup vs baseline: 9.1378x; 9.1378x over previous
//
#include <hip/hip_runtime.h>
#include <float.h>
#include <math.h>

// Problem constants (from reference)
constexpr int B  = 16;
constexpr int VS = 10475;
constexpr int VO = 8192;
constexpr int K  = 64;
constexpr int PS = 1024;
constexpr int PO = 2048;

// Geometry: 256 blocks (1/CU) x 256 threads. Block = (k, 256-query chunk).
// Full j-range (2048 objects) in LDS; 8 half-wave jgroups x 256 j each;
// each lane owns 8 queries (4 packed f32 pairs).
constexpr int BLK  = 256;
constexpr int GRID = K * (PS / 256);   // 256
constexpr int NG   = 8;                // jgroups per block (32 lanes each)
constexpr int JPG  = PO / NG;          // 256 objects per jgroup
constexpr int QPB  = 256;              // queries per block
constexpr int QL   = 8;                // queries per lane

typedef float v2f __attribute__((ext_vector_type(2)));
typedef float v4f __attribute__((ext_vector_type(4)));

// ---------------- kernel 1: full min + block partial sum ----------------

__global__ __launch_bounds__(BLK)
void cl_onepass(const float* __restrict__ smplx_v,
                const float* __restrict__ object_v,
                const int*   __restrict__ spi,
                const int*   __restrict__ opi,
                const int*   __restrict__ bidx,
                float*       __restrict__ partial)   // [GRID]
{
    __shared__ v4f    so[PO];        // (x,y,z, 0.5*|o|^2) -> 32 KiB
    __shared__ float4 qld[QPB];      // (x,y,z, |s|^2)     ->  4 KiB
    __shared__ float  red[NG][QPB];  //                    ->  8 KiB
    __shared__ float  rsum[BLK];

    const int bk  = blockIdx.x;
    const int tid = threadIdx.x;
    const int k   = bk >> 2;
    const int ic  = bk & 3;
    const int b   = bidx[k];

    // ---- gather: all 2048 objects of this k into LDS ----
    const float* __restrict__ ov = object_v + (size_t)b * VO * 3;
    #pragma unroll
    for (int r = 0; r < PO / BLK; ++r) {
        const int j  = r * BLK + tid;
        const int oj = opi[k * PO + j];
        const float x = ov[oj * 3 + 0];
        const float y = ov[oj * 3 + 1];
        const float z = ov[oj * 3 + 2];
        so[j] = (v4f){x, y, z, 0.5f * (x * x + y * y + z * z)};
    }
    // ---- gather: this block's 256 queries ----
    {
        const int i  = ic * QPB + tid;
        const int si = spi[k * PS + i];
        const float* __restrict__ sv = smplx_v + ((size_t)b * VS + si) * 3;
        const float x = sv[0], y = sv[1], z = sv[2];
        qld[tid] = make_float4(x, y, z, x * x + y * y + z * z);
    }
    __syncthreads();

    // ---- setup: lane owns 8 queries as 4 packed pairs ----
    const int g  = tid >> 5;         // jgroup 0..7 (half-wave)
    const int gl = tid & 31;
    const int qb = gl * QL;

    v2f nsx[4], nsy[4], nsz[4], mint[4];
    #pragma unroll
    for (int p = 0; p < 4; ++p) {
        const float4 qa = qld[qb + 2 * p];
        const float4 qc = qld[qb + 2 * p + 1];
        nsx[p] = (v2f){-qa.x, -qc.x};
        nsy[p] = (v2f){-qa.y, -qc.y};
        nsz[p] = (v2f){-qa.z, -qc.z};
        mint[p] = (v2f){FLT_MAX, FLT_MAX};
    }

    // ---- hot loop: min over this jgroup's 256 objects ----
    // t = 0.5*|o|^2 - s.o  computed for 2 queries per v_pk_fma_f32.
    // op_sel splats o.x / o.y / o.z / o.w straight out of the (x,y),(z,w)
    // register pairs: op_sel[i]/op_sel_hi[i] pick the dword of src i used
    // for the lo/hi result.
    const v4f* __restrict__ sog = &so[g * JPG];
    #pragma unroll 8
    for (int j = 0; j < JPG; ++j) {
        const v4f o = sog[j];
        const v2f oxy = __builtin_shufflevector(o, o, 0, 1);  // (x,y)
        const v2f ozw = __builtin_shufflevector(o, o, 2, 3);  // (z,w)
        #pragma unroll
        for (int p = 0; p < 4; ++p) {
            v2f t;
            // t = splat(x)*nsx + splat(w)
            asm("v_pk_fma_f32 %0, %1, %2, %3 op_sel:[0,0,1] op_sel_hi:[0,1,1]"
                : "=v"(t) : "v"(oxy), "v"(nsx[p]), "v"(ozw));
            // t = splat(y)*nsy + t
            asm("v_pk_fma_f32 %0, %1, %2, %0 op_sel:[1,0,0] op_sel_hi:[1,1,1]"
                : "+v"(t) : "v"(oxy), "v"(nsy[p]));
            // t = splat(z)*nsz + t
            asm("v_pk_fma_f32 %0, %1, %2, %0 op_sel:[0,0,0] op_sel_hi:[0,1,1]"
                : "+v"(t) : "v"(ozw), "v"(nsz[p]));
            mint[p].x = fminf(mint[p].x, t.x);
            mint[p].y = fminf(mint[p].y, t.y);
        }
    }

    // ---- cross-jgroup min via LDS ----
    #pragma unroll
    for (int p = 0; p < 4; ++p) {
        red[g][qb + 2 * p]     = mint[p].x;
        red[g][qb + 2 * p + 1] = mint[p].y;
    }
    __syncthreads();

    // thread t finalizes query t of this block
    float m = red[0][tid];
    #pragma unroll
    for (int g2 = 1; g2 < NG; ++g2) m = fminf(m, red[g2][tid]);
    const float s2q = qld[tid].w;
    const float d   = sqrtf(fmaxf(fmaf(2.0f, m, s2q), 0.0f));

    // ---- deterministic block tree-sum ----
    rsum[tid] = d;
    __syncthreads();
    for (int s = BLK / 2; s > 0; s >>= 1) {
        if (tid < s) rsum[tid] += rsum[tid + s];
        __syncthreads();
    }
    if (tid == 0) partial[bk] = rsum[0];
}

// ---------------- kernel 2: final 256 -> 1 reduce ----------------

__global__ __launch_bounds__(GRID)
void cl_final(const float* __restrict__ partial, float* __restrict__ out)
{
    __shared__ float red[GRID];
    const int tid = threadIdx.x;
    red[tid] = partial[tid];
    __syncthreads();
    for (int s = GRID / 2; s > 0; s >>= 1) {
        if (tid < s) red[tid] += red[tid + s];
        __syncthreads();
    }
    if (tid == 0) out[0] = red[0] * (1.0f / (float)(K * PS));
}

// ---------------- launcher ----------------

extern "C" void kernel_launch(void* const* d_in, const int* in_sizes, int n_in,
                              void* d_out, int out_size, void* d_ws, size_t ws_size,
                              hipStream_t stream)
{
    const float* smplx_v       = (const float*)d_in[0];
    const float* object_v      = (const float*)d_in[1];
    const int*   smpl_part_idx = (const int*)d_in[2];
    const int*   obj_part_idx  = (const int*)d_in[3];
    const int*   batch_idx     = (const int*)d_in[4];
    float*       out           = (float*)d_out;

    float* partial = (float*)d_ws;   // GRID floats

    cl_onepass<<<GRID, BLK, 0, stream>>>(
        smplx_v, object_v, smpl_part_idx, obj_part_idx, batch_idx, partial);
    cl_final<<<1, GRID, 0, stream>>>(partial, out);
}